// Round 11
// baseline (163.407 us; speedup 1.0000x reference)
//
#include <hip/hip_runtime.h>
#include <cstdint>
#include <cstddef>

#define F_IN 256
#define F_OUT 128
#define NEG_SLOPE 0.2f
#define NPB 64          // nodes per bucket (dloc packs into 6 bits)
#define MAXBUK 1024     // supports N <= 65536
#define BCAP 2048       // slots per bucket region (mean 1024, 32-sigma safe)
#define EPB 2048        // edges per build block (256 thr x 8); grid stays co-resident
#define WT_STRIDE 72    // 64 + 8 pad (bf16 elems)

typedef short short8 __attribute__((ext_vector_type(8)));
typedef float f32x4 __attribute__((ext_vector_type(4)));

__device__ __forceinline__ unsigned short f2bf_rne(float f) {
  unsigned u = __float_as_uint(f);
  u += 0x7FFFu + ((u >> 16) & 1u);   // round-to-nearest-even
  return (unsigned short)(u >> 16);
}

// packed fp32x2 -> bf16x2 (RNE), single HW instruction; identical rounding to f2bf_rne
__device__ __forceinline__ unsigned cvt_pk_bf16(float lo, float hi) {
  unsigned r;
  asm volatile("v_cvt_pk_bf16_f32 %0, %1, %2" : "=v"(r) : "v"(lo), "v"(hi));
  return r;
}

__device__ __forceinline__ float bf_lo(unsigned u) { return __uint_as_float(u << 16); }
__device__ __forceinline__ float bf_hi(unsigned u) { return __uint_as_float(u & 0xFFFF0000u); }

// ---------------- setup: cast+transpose W -> Wt[n][k] bf16, bucketcnt=0 ----------------
__global__ __launch_bounds__(256) void setup_kernel(const float* __restrict__ W,
                                                    unsigned short* __restrict__ Wt,
                                                    int* __restrict__ bucketcnt, int nbuk) {
  int idx = blockIdx.x * 256 + threadIdx.x;
  if (idx < F_IN * F_OUT) {
    int n = idx & 127, k = idx >> 7;
    Wt[(size_t)n * F_IN + k] = f2bf_rne(W[(size_t)k * F_OUT + n]);
  }
  if (idx < nbuk) bucketcnt[idx] = 0;
}

// ---------------- fused GEMM + edge-bucket build ----------------
// blocks [0, buildBlocks)           : edge multisplit -> packed bucket regions (EPB=2048)
// blocks [buildBlocks, +gemmBlocks) : h = x @ W, 128 rows/block (2 m-tiles share each
//                                     B-fragment ds_read -> 2 MFMAs per ds_read)
// 391 + 391 = 782 blocks, 4 blocks/CU => fully co-resident; build overlap preserved
// AND 2x the build parallelism of the EPB=4096 config (R7's confound removed).
__global__ __launch_bounds__(256, 4) void gemm_build_kernel(
    const float* __restrict__ x, const unsigned short* __restrict__ Wt,
    const float* __restrict__ att_src, const float* __restrict__ att_dst,
    unsigned short* __restrict__ hb, float* __restrict__ a_src, float* __restrict__ a_dst,
    int N, const int* __restrict__ ei, int* __restrict__ bucketcnt,
    unsigned* __restrict__ csrw, int E, int nbuk, int buildBlocks) {
  __shared__ __attribute__((aligned(16))) char lds_raw[128 * WT_STRIDE * 2];  // 18432 B
  const int tid = threadIdx.x;

  if ((int)blockIdx.x < buildBlocks) {
    // ---------------- build branch ----------------
    int* lhist = (int*)lds_raw;               // MAXBUK ints
    int* gbase = (int*)(lds_raw + 4096);      // MAXBUK ints
    const int e0 = blockIdx.x * EPB;
    for (int i = tid; i < nbuk; i += 256) lhist[i] = 0;
    __syncthreads();
    int lr[8], lb[8];
    unsigned lw[8];
#pragma unroll
    for (int i = 0; i < 8; ++i) {
      int e = e0 + i * 256 + tid;
      lb[i] = -1;
      if (e < E) {
        int s = ei[e], d = ei[E + e];
        lb[i] = d >> 6;
        lw[i] = ((unsigned)(d & 63) << 26) | (unsigned)s;
        lr[i] = atomicAdd(&lhist[lb[i]], 1);   // LDS atomic: local rank
      }
    }
    __syncthreads();
    for (int i = tid; i < nbuk; i += 256) {
      int c = lhist[i];
      if (c > 0) gbase[i] = atomicAdd(&bucketcnt[i], c);  // one global atomic per bucket
    }
    __syncthreads();
#pragma unroll
    for (int i = 0; i < 8; ++i) {
      if (lb[i] >= 0) {
        int off = gbase[lb[i]] + lr[i];
        if (off < BCAP) csrw[(size_t)lb[i] * BCAP + off] = lw[i];
      }
    }
    return;
  }

  // ---------------- gemm branch: 128 rows per block (2 m-tiles) ----------------
  unsigned short* wt_l = (unsigned short*)lds_raw;   // 128 * WT_STRIDE bf16
  const int bid  = blockIdx.x - buildBlocks;
  const int lane = tid & 63;
  const int wv   = tid >> 6;
  const int q    = lane >> 4;
  const int l16  = lane & 15;
  const int m0   = bid * 128;
  const int mA   = m0 + wv * 16 + l16;        // tile 0 row
  const int mB   = mA + 64;                   // tile 1 row
  const int mcA  = (mA < N) ? mA : (N - 1);
  const int mcB  = (mB < N) ? mB : (N - 1);

  f32x4 accA[8], accB[8];
#pragma unroll
  for (int i = 0; i < 8; ++i) { accA[i] = (f32x4)(0.f); accB[i] = (f32x4)(0.f); }

  const int srow  = tid >> 1;
  const int shalf = tid & 1;

#pragma unroll 1
  for (int t = 0; t < 4; ++t) {
    {
      const unsigned short* g = Wt + (size_t)srow * F_IN + t * 64 + shalf * 32;
      unsigned short* l = wt_l + srow * WT_STRIDE + shalf * 32;
#pragma unroll
      for (int j = 0; j < 4; ++j)
        *(uint4*)(l + j * 8) = *(const uint4*)(g + j * 8);
    }
    __syncthreads();

#pragma unroll
    for (int s = 0; s < 2; ++s) {
      const int kg = t * 64 + s * 32 + q * 8;
      f32x4 a0 = *(const f32x4*)(x + (size_t)mcA * F_IN + kg);
      f32x4 a1 = *(const f32x4*)(x + (size_t)mcA * F_IN + kg + 4);
      f32x4 b0 = *(const f32x4*)(x + (size_t)mcB * F_IN + kg);
      f32x4 b1 = *(const f32x4*)(x + (size_t)mcB * F_IN + kg + 4);
      union { short8 s8; unsigned u[4]; } ca, cb;
      ca.u[0] = cvt_pk_bf16(a0[0], a0[1]);
      ca.u[1] = cvt_pk_bf16(a0[2], a0[3]);
      ca.u[2] = cvt_pk_bf16(a1[0], a1[1]);
      ca.u[3] = cvt_pk_bf16(a1[2], a1[3]);
      cb.u[0] = cvt_pk_bf16(b0[0], b0[1]);
      cb.u[1] = cvt_pk_bf16(b0[2], b0[3]);
      cb.u[2] = cvt_pk_bf16(b1[0], b1[1]);
      cb.u[3] = cvt_pk_bf16(b1[2], b1[3]);
      short8 avA = ca.s8, avB = cb.s8;
#pragma unroll
      for (int nt = 0; nt < 8; ++nt) {
        short8 bv = *(const short8*)(wt_l + (nt * 16 + l16) * WT_STRIDE + s * 32 + q * 8);
        accA[nt] = __builtin_amdgcn_mfma_f32_16x16x32_bf16(avA, bv, accA[nt], 0, 0, 0);
        accB[nt] = __builtin_amdgcn_mfma_f32_16x16x32_bf16(avB, bv, accB[nt], 0, 0, 0);
      }
    }
    __syncthreads();
  }

  float as_c[8], ad_c[8];
#pragma unroll
  for (int nt = 0; nt < 8; ++nt) {
    as_c[nt] = att_src[nt * 16 + l16];
    ad_c[nt] = att_dst[nt * 16 + l16];
  }
  float psA[4] = {0, 0, 0, 0}, pdA[4] = {0, 0, 0, 0};
  float psB[4] = {0, 0, 0, 0}, pdB[4] = {0, 0, 0, 0};
#pragma unroll
  for (int nt = 0; nt < 8; ++nt)
#pragma unroll
    for (int r = 0; r < 4; ++r) {
      psA[r] += accA[nt][r] * as_c[nt];
      pdA[r] += accA[nt][r] * ad_c[nt];
      psB[r] += accB[nt][r] * as_c[nt];
      pdB[r] += accB[nt][r] * ad_c[nt];
    }
#pragma unroll
  for (int r = 0; r < 4; ++r) {
    int gmA = m0 + wv * 16 + q * 4 + r;
    int gmB = gmA + 64;
    if (gmA < N) {
#pragma unroll
      for (int nt = 0; nt < 8; ++nt)
        hb[(size_t)gmA * F_OUT + nt * 16 + l16] = f2bf_rne(accA[nt][r]);
    }
    if (gmB < N) {
#pragma unroll
      for (int nt = 0; nt < 8; ++nt)
        hb[(size_t)gmB * F_OUT + nt * 16 + l16] = f2bf_rne(accB[nt][r]);
    }
  }
#pragma unroll
  for (int r = 0; r < 4; ++r) {
#pragma unroll
    for (int off = 1; off <= 8; off <<= 1) {
      psA[r] += __shfl_xor(psA[r], off, 64);
      pdA[r] += __shfl_xor(pdA[r], off, 64);
      psB[r] += __shfl_xor(psB[r], off, 64);
      pdB[r] += __shfl_xor(pdB[r], off, 64);
    }
  }
  if (l16 == 0) {
#pragma unroll
    for (int r = 0; r < 4; ++r) {
      int gmA = m0 + wv * 16 + q * 4 + r;
      int gmB = gmA + 64;
      if (gmA < N) { a_src[gmA] = psA[r]; a_dst[gmA] = pdA[r]; }
      if (gmB < N) { a_src[gmB] = psB[r]; a_dst[gmB] = pdB[r]; }
    }
  }
}

// ---------------- aggregate: in-LDS counting sort + register gather (R6-proven) ----------------
// One block per 64-node bucket. Prologue: counting sort into node-sorted LDS list.
// Main loop: 16 lanes/node, 8-slot chunks, shfl broadcast, uint4 row gathers.
// p=exp(leaky(e)) without max shift (|e|<~12; alpha identical after normalization).
__global__ __launch_bounds__(256) void aggregate_kernel(const unsigned short* __restrict__ hb,
                                                        const unsigned* __restrict__ csrw,
                                                        const float* __restrict__ a_src,
                                                        const float* __restrict__ a_dst,
                                                        const int* __restrict__ bucketcnt,
                                                        const float* __restrict__ bias,
                                                        float* __restrict__ out, int N) {
  __shared__ unsigned sw[BCAP];
  __shared__ unsigned sorted[BCAP + NPB];
  __shared__ int start[NPB + 1];
  __shared__ int fill[NPB];
  __shared__ float adl[NPB];
  const int tid = threadIdx.x;
  const int n0  = blockIdx.x * NPB;
  int cnt = bucketcnt[blockIdx.x];
  cnt = (cnt < BCAP) ? cnt : BCAP;

  if (tid < NPB) {
    int n = n0 + tid;
    start[1 + tid] = (n < N) ? 1 : 0;   // self-loop slot
    fill[tid] = 1;                      // slot 0 reserved for self loop
    adl[tid] = (n < N) ? a_dst[n] : 0.f;
  }
  __syncthreads();
  for (int j = tid; j < cnt; j += 256) {
    unsigned w = csrw[(size_t)blockIdx.x * BCAP + j];
    sw[j] = w;
    atomicAdd(&start[1 + (int)(w >> 26)], 1);
  }
  __syncthreads();
  if (tid < NPB) {                      // wave 0: exclusive scan of 64 counts
    int incl = start[1 + tid];
#pragma unroll
    for (int off = 1; off < NPB; off <<= 1) {
      int t = __shfl_up(incl, off, 64);
      if (tid >= off) incl += t;
    }
    start[1 + tid] = incl;
    if (tid == 0) start[0] = 0;
  }
  __syncthreads();
  if (tid < NPB && n0 + tid < N)
    sorted[start[tid]] = ((unsigned)tid << 26) | (unsigned)(n0 + tid);  // self loop
  for (int j = tid; j < cnt; j += 256) {
    unsigned w = sw[j];
    int loc = (int)(w >> 26);
    sorted[start[loc] + atomicAdd(&fill[loc], 1)] = w;
  }
  __syncthreads();

  const int g   = tid >> 4;   // 16 groups; group handles nodes g, g+16, g+32, g+48
  const int l16 = tid & 15;
  const unsigned short* hrow = hb + l16 * 8;
  const float4 bb0 = *(const float4*)(bias + l16 * 8);
  const float4 bb1 = *(const float4*)(bias + l16 * 8 + 4);
#pragma unroll 1
  for (int r = 0; r < 4; ++r) {
    int loc = g + r * 16;
    int n = n0 + loc;
    if (n >= N) continue;
    int b0 = start[loc], b1 = start[loc + 1];
    f32x4 acc0 = (f32x4)(0.f), acc1 = (f32x4)(0.f);
    float s = 0.f;
    for (int jb = b0; jb < b1; jb += 8) {
      int jj = jb + (l16 & 7);
      float p = 0.f;
      int c = 0;
      if (jj < b1) {
        unsigned w = sorted[jj];
        c = (int)(w & 0x03FFFFFFu);
        float e = a_src[c] + adl[loc];
        e = (e > 0.f) ? e : NEG_SLOPE * e;
        p = __expf(e);
      }
      s += (l16 < 8) ? p : 0.f;
#pragma unroll
      for (int k = 0; k < 8; ++k) {
        float pk = __shfl(p, k, 8);
        int   ck = __shfl(c, k, 8);
        const uint4 hv = *(const uint4*)(hrow + (size_t)ck * F_OUT);
        acc0[0] += pk * bf_lo(hv.x); acc0[1] += pk * bf_hi(hv.x);
        acc0[2] += pk * bf_lo(hv.y); acc0[3] += pk * bf_hi(hv.y);
        acc1[0] += pk * bf_lo(hv.z); acc1[1] += pk * bf_hi(hv.z);
        acc1[2] += pk * bf_lo(hv.w); acc1[3] += pk * bf_hi(hv.w);
      }
    }
#pragma unroll
    for (int off = 1; off < 16; off <<= 1) s += __shfl_xor(s, off, 16);

    float sc = 1.f / (s + 1e-16f);
    float4 o0, o1;
    o0.x = acc0[0] * sc + bb0.x;
    o0.y = acc0[1] * sc + bb0.y;
    o0.z = acc0[2] * sc + bb0.z;
    o0.w = acc0[3] * sc + bb0.w;
    o1.x = acc1[0] * sc + bb1.x;
    o1.y = acc1[1] * sc + bb1.y;
    o1.z = acc1[2] * sc + bb1.z;
    o1.w = acc1[3] * sc + bb1.w;
    *(float4*)&out[(size_t)n * F_OUT + l16 * 8]     = o0;
    *(float4*)&out[(size_t)n * F_OUT + l16 * 8 + 4] = o1;
  }
}

// ---------------- launch ----------------
extern "C" void kernel_launch(void* const* d_in, const int* in_sizes, int n_in,
                              void* d_out, int out_size, void* d_ws, size_t ws_size,
                              hipStream_t stream) {
  const float* x     = (const float*)d_in[0];
  const int*   ei    = (const int*)d_in[1];
  const float* W     = (const float*)d_in[2];
  const float* att_s = (const float*)d_in[3];
  const float* att_d = (const float*)d_in[4];
  const float* bias  = (const float*)d_in[5];
  float* out = (float*)d_out;

  const int N = in_sizes[0] / F_IN;
  const int E = in_sizes[1] / 2;
  const int nbuk = (N + NPB - 1) / NPB;
  const int gemmBlocks  = (N + 127) / 128;
  const int buildBlocks = (E + EPB - 1) / EPB;

  char* p = (char*)d_ws;
  unsigned short* wt = (unsigned short*)p; p += (size_t)F_IN * F_OUT * sizeof(unsigned short);
  unsigned short* hb = (unsigned short*)p; p += (size_t)N * F_OUT * sizeof(unsigned short);
  float* a_src = (float*)p;  p += (size_t)N * sizeof(float);
  float* a_dst = (float*)p;  p += (size_t)N * sizeof(float);
  int*   bcnt  = (int*)p;    p += (size_t)nbuk * sizeof(int);
  p = (char*)(((uintptr_t)p + 15) & ~(uintptr_t)15);
  unsigned* csrw = (unsigned*)p; p += (size_t)nbuk * BCAP * sizeof(unsigned);

  int setup_n = (F_IN * F_OUT > nbuk) ? F_IN * F_OUT : nbuk;
  setup_kernel<<<(setup_n + 255) / 256, 256, 0, stream>>>(W, wt, bcnt, nbuk);
  gemm_build_kernel<<<buildBlocks + gemmBlocks, 256, 0, stream>>>(
      x, wt, att_s, att_d, hb, a_src, a_dst, N, ei, bcnt, csrw, E, nbuk, buildBlocks);
  aggregate_kernel<<<nbuk, 256, 0, stream>>>(hb, csrw, a_src, a_dst, bcnt, bias, out, N);
}

// Round 12
// 154.489 us; speedup vs baseline: 1.0577x; 1.0577x over previous
//
#include <hip/hip_runtime.h>
#include <cstdint>
#include <cstddef>

#define F_IN 256
#define F_OUT 128
#define NEG_SLOPE 0.2f
#define NPB 64          // nodes per bucket (dloc packs into 6 bits)
#define MAXBUK 1024     // supports N <= 65536
#define BCAP 2048       // slots per bucket region (mean 1024, 32-sigma safe)
#define EPB 4096        // edges per build block (256 thr x 16) -> 978 blocks co-resident
#define CNT_STRIDE 16   // one bucket counter per 64B line -> atomics spread across L2 channels
#define WT_STRIDE 72    // 64 + 8 pad (bf16 elems)

typedef short short8 __attribute__((ext_vector_type(8)));
typedef float f32x4 __attribute__((ext_vector_type(4)));

__device__ __forceinline__ unsigned short f2bf_rne(float f) {
  unsigned u = __float_as_uint(f);
  u += 0x7FFFu + ((u >> 16) & 1u);   // round-to-nearest-even
  return (unsigned short)(u >> 16);
}

// packed fp32x2 -> bf16x2 (RNE), single HW instruction; identical rounding to f2bf_rne
__device__ __forceinline__ unsigned cvt_pk_bf16(float lo, float hi) {
  unsigned r;
  asm volatile("v_cvt_pk_bf16_f32 %0, %1, %2" : "=v"(r) : "v"(lo), "v"(hi));
  return r;
}

__device__ __forceinline__ float bf_lo(unsigned u) { return __uint_as_float(u << 16); }
__device__ __forceinline__ float bf_hi(unsigned u) { return __uint_as_float(u & 0xFFFF0000u); }

// ---------------- setup: cast+transpose W -> Wt[n][k] bf16, bucketcnt=0 ----------------
__global__ __launch_bounds__(256) void setup_kernel(const float* __restrict__ W,
                                                    unsigned short* __restrict__ Wt,
                                                    int* __restrict__ bucketcnt, int nbuk) {
  int idx = blockIdx.x * 256 + threadIdx.x;
  if (idx < F_IN * F_OUT) {
    int n = idx & 127, k = idx >> 7;
    Wt[(size_t)n * F_IN + k] = f2bf_rne(W[(size_t)k * F_OUT + n]);
  }
  if (idx < nbuk * CNT_STRIDE) bucketcnt[idx] = 0;
}

// ---------------- fused GEMM + edge-bucket build (R6 structure + padded atomics) ----------------
// blocks [0, buildBlocks)           : edge multisplit -> packed bucket regions
// blocks [buildBlocks, +gemmBlocks) : h = x @ W (bf16 MFMA) + fused attention logits
// 978 total blocks, 4 blocks/CU resident => full overlap of build under gemm.
// bucketcnt is padded to 1 counter / 64B line: ~150k per-bucket atomics spread over
// 782 lines (all L2 channels) instead of 49 lines (~12 channels) -> no atomic serialization.
__global__ __launch_bounds__(256, 4) void gemm_build_kernel(
    const float* __restrict__ x, const unsigned short* __restrict__ Wt,
    const float* __restrict__ att_src, const float* __restrict__ att_dst,
    unsigned short* __restrict__ hb, float* __restrict__ a_src, float* __restrict__ a_dst,
    int N, const int* __restrict__ ei, int* __restrict__ bucketcnt,
    unsigned* __restrict__ csrw, int E, int nbuk, int buildBlocks) {
  __shared__ __attribute__((aligned(16))) char lds_raw[128 * WT_STRIDE * 2];  // 18432 B
  const int tid = threadIdx.x;

  if ((int)blockIdx.x < buildBlocks) {
    // ---------------- build branch ----------------
    int* lhist = (int*)lds_raw;               // MAXBUK ints
    int* gbase = (int*)(lds_raw + 4096);      // MAXBUK ints
    const int e0 = blockIdx.x * EPB;
    for (int i = tid; i < nbuk; i += 256) lhist[i] = 0;
    __syncthreads();
    int lr[16], lb[16];
    unsigned lw[16];
#pragma unroll
    for (int i = 0; i < 16; ++i) {
      int e = e0 + i * 256 + tid;
      lb[i] = -1;
      if (e < E) {
        int s = ei[e], d = ei[E + e];
        lb[i] = d >> 6;
        lw[i] = ((unsigned)(d & 63) << 26) | (unsigned)s;
        lr[i] = atomicAdd(&lhist[lb[i]], 1);   // LDS atomic: local rank
      }
    }
    __syncthreads();
    for (int i = tid; i < nbuk; i += 256) {
      int c = lhist[i];
      if (c > 0) gbase[i] = atomicAdd(&bucketcnt[i * CNT_STRIDE], c);  // padded line
    }
    __syncthreads();
#pragma unroll
    for (int i = 0; i < 16; ++i) {
      if (lb[i] >= 0) {
        int off = gbase[lb[i]] + lr[i];
        if (off < BCAP) csrw[(size_t)lb[i] * BCAP + off] = lw[i];
      }
    }
    return;
  }

  // ---------------- gemm branch (R6-proven 64-row tile) ----------------
  unsigned short* wt_l = (unsigned short*)lds_raw;   // 128 * WT_STRIDE bf16
  const int bid  = blockIdx.x - buildBlocks;
  const int lane = tid & 63;
  const int wv   = tid >> 6;
  const int q    = lane >> 4;
  const int l16  = lane & 15;
  const int m0   = bid * 64;
  const int m    = m0 + wv * 16 + l16;
  const int mc   = (m < N) ? m : (N - 1);

  f32x4 acc[8];
#pragma unroll
  for (int i = 0; i < 8; ++i) acc[i] = (f32x4)(0.f);

  const int srow  = tid >> 1;
  const int shalf = tid & 1;

#pragma unroll 1
  for (int t = 0; t < 4; ++t) {
    {
      const unsigned short* g = Wt + (size_t)srow * F_IN + t * 64 + shalf * 32;
      unsigned short* l = wt_l + srow * WT_STRIDE + shalf * 32;
#pragma unroll
      for (int j = 0; j < 4; ++j)
        *(uint4*)(l + j * 8) = *(const uint4*)(g + j * 8);
    }
    __syncthreads();

#pragma unroll
    for (int s = 0; s < 2; ++s) {
      const int kg = t * 64 + s * 32 + q * 8;
      f32x4 a0 = *(const f32x4*)(x + (size_t)mc * F_IN + kg);
      f32x4 a1 = *(const f32x4*)(x + (size_t)mc * F_IN + kg + 4);
      union { short8 s8; unsigned u[4]; } cvt;
      cvt.u[0] = cvt_pk_bf16(a0[0], a0[1]);
      cvt.u[1] = cvt_pk_bf16(a0[2], a0[3]);
      cvt.u[2] = cvt_pk_bf16(a1[0], a1[1]);
      cvt.u[3] = cvt_pk_bf16(a1[2], a1[3]);
      short8 av = cvt.s8;
#pragma unroll
      for (int nt = 0; nt < 8; ++nt) {
        short8 bv = *(const short8*)(wt_l + (nt * 16 + l16) * WT_STRIDE + s * 32 + q * 8);
        acc[nt] = __builtin_amdgcn_mfma_f32_16x16x32_bf16(av, bv, acc[nt], 0, 0, 0);
      }
    }
    __syncthreads();
  }

  float as_c[8], ad_c[8];
#pragma unroll
  for (int nt = 0; nt < 8; ++nt) {
    as_c[nt] = att_src[nt * 16 + l16];
    ad_c[nt] = att_dst[nt * 16 + l16];
  }
  float ps[4] = {0.f, 0.f, 0.f, 0.f}, pd[4] = {0.f, 0.f, 0.f, 0.f};
#pragma unroll
  for (int nt = 0; nt < 8; ++nt)
#pragma unroll
    for (int r = 0; r < 4; ++r) {
      ps[r] += acc[nt][r] * as_c[nt];
      pd[r] += acc[nt][r] * ad_c[nt];
    }
#pragma unroll
  for (int r = 0; r < 4; ++r) {
    int gm = m0 + wv * 16 + q * 4 + r;
    if (gm < N) {
#pragma unroll
      for (int nt = 0; nt < 8; ++nt)
        hb[(size_t)gm * F_OUT + nt * 16 + l16] = f2bf_rne(acc[nt][r]);
    }
  }
#pragma unroll
  for (int r = 0; r < 4; ++r) {
#pragma unroll
    for (int off = 1; off <= 8; off <<= 1) {
      ps[r] += __shfl_xor(ps[r], off, 64);
      pd[r] += __shfl_xor(pd[r], off, 64);
    }
  }
  if (l16 == 0) {
#pragma unroll
    for (int r = 0; r < 4; ++r) {
      int gm = m0 + wv * 16 + q * 4 + r;
      if (gm < N) { a_src[gm] = ps[r]; a_dst[gm] = pd[r]; }
    }
  }
}

// ---------------- aggregate: in-LDS counting sort + register gather (R6-proven) ----------------
// One block per 64-node bucket. Prologue: counting sort into node-sorted LDS list.
// Main loop: 16 lanes/node, 8-slot chunks, shfl broadcast, uint4 row gathers.
// p=exp(leaky(e)) without max shift (|e|<~12; alpha identical after normalization).
__global__ __launch_bounds__(256) void aggregate_kernel(const unsigned short* __restrict__ hb,
                                                        const unsigned* __restrict__ csrw,
                                                        const float* __restrict__ a_src,
                                                        const float* __restrict__ a_dst,
                                                        const int* __restrict__ bucketcnt,
                                                        const float* __restrict__ bias,
                                                        float* __restrict__ out, int N) {
  __shared__ unsigned sw[BCAP];
  __shared__ unsigned sorted[BCAP + NPB];
  __shared__ int start[NPB + 1];
  __shared__ int fill[NPB];
  __shared__ float adl[NPB];
  const int tid = threadIdx.x;
  const int n0  = blockIdx.x * NPB;
  int cnt = bucketcnt[blockIdx.x * CNT_STRIDE];
  cnt = (cnt < BCAP) ? cnt : BCAP;

  if (tid < NPB) {
    int n = n0 + tid;
    start[1 + tid] = (n < N) ? 1 : 0;   // self-loop slot
    fill[tid] = 1;                      // slot 0 reserved for self loop
    adl[tid] = (n < N) ? a_dst[n] : 0.f;
  }
  __syncthreads();
  for (int j = tid; j < cnt; j += 256) {
    unsigned w = csrw[(size_t)blockIdx.x * BCAP + j];
    sw[j] = w;
    atomicAdd(&start[1 + (int)(w >> 26)], 1);
  }
  __syncthreads();
  if (tid < NPB) {                      // wave 0: exclusive scan of 64 counts
    int incl = start[1 + tid];
#pragma unroll
    for (int off = 1; off < NPB; off <<= 1) {
      int t = __shfl_up(incl, off, 64);
      if (tid >= off) incl += t;
    }
    start[1 + tid] = incl;
    if (tid == 0) start[0] = 0;
  }
  __syncthreads();
  if (tid < NPB && n0 + tid < N)
    sorted[start[tid]] = ((unsigned)tid << 26) | (unsigned)(n0 + tid);  // self loop
  for (int j = tid; j < cnt; j += 256) {
    unsigned w = sw[j];
    int loc = (int)(w >> 26);
    sorted[start[loc] + atomicAdd(&fill[loc], 1)] = w;
  }
  __syncthreads();

  const int g   = tid >> 4;   // 16 groups; group handles nodes g, g+16, g+32, g+48
  const int l16 = tid & 15;
  const unsigned short* hrow = hb + l16 * 8;
  const float4 bb0 = *(const float4*)(bias + l16 * 8);
  const float4 bb1 = *(const float4*)(bias + l16 * 8 + 4);
#pragma unroll 1
  for (int r = 0; r < 4; ++r) {
    int loc = g + r * 16;
    int n = n0 + loc;
    if (n >= N) continue;
    int b0 = start[loc], b1 = start[loc + 1];
    f32x4 acc0 = (f32x4)(0.f), acc1 = (f32x4)(0.f);
    float s = 0.f;
    for (int jb = b0; jb < b1; jb += 8) {
      int jj = jb + (l16 & 7);
      float p = 0.f;
      int c = 0;
      if (jj < b1) {
        unsigned w = sorted[jj];
        c = (int)(w & 0x03FFFFFFu);
        float e = a_src[c] + adl[loc];
        e = (e > 0.f) ? e : NEG_SLOPE * e;
        p = __expf(e);
      }
      s += (l16 < 8) ? p : 0.f;
#pragma unroll
      for (int k = 0; k < 8; ++k) {
        float pk = __shfl(p, k, 8);
        int   ck = __shfl(c, k, 8);
        const uint4 hv = *(const uint4*)(hrow + (size_t)ck * F_OUT);
        acc0[0] += pk * bf_lo(hv.x); acc0[1] += pk * bf_hi(hv.x);
        acc0[2] += pk * bf_lo(hv.y); acc0[3] += pk * bf_hi(hv.y);
        acc1[0] += pk * bf_lo(hv.z); acc1[1] += pk * bf_hi(hv.z);
        acc1[2] += pk * bf_lo(hv.w); acc1[3] += pk * bf_hi(hv.w);
      }
    }
#pragma unroll
    for (int off = 1; off < 16; off <<= 1) s += __shfl_xor(s, off, 16);

    float sc = 1.f / (s + 1e-16f);
    float4 o0, o1;
    o0.x = acc0[0] * sc + bb0.x;
    o0.y = acc0[1] * sc + bb0.y;
    o0.z = acc0[2] * sc + bb0.z;
    o0.w = acc0[3] * sc + bb0.w;
    o1.x = acc1[0] * sc + bb1.x;
    o1.y = acc1[1] * sc + bb1.y;
    o1.z = acc1[2] * sc + bb1.z;
    o1.w = acc1[3] * sc + bb1.w;
    *(float4*)&out[(size_t)n * F_OUT + l16 * 8]     = o0;
    *(float4*)&out[(size_t)n * F_OUT + l16 * 8 + 4] = o1;
  }
}

// ---------------- launch ----------------
extern "C" void kernel_launch(void* const* d_in, const int* in_sizes, int n_in,
                              void* d_out, int out_size, void* d_ws, size_t ws_size,
                              hipStream_t stream) {
  const float* x     = (const float*)d_in[0];
  const int*   ei    = (const int*)d_in[1];
  const float* W     = (const float*)d_in[2];
  const float* att_s = (const float*)d_in[3];
  const float* att_d = (const float*)d_in[4];
  const float* bias  = (const float*)d_in[5];
  float* out = (float*)d_out;

  const int N = in_sizes[0] / F_IN;
  const int E = in_sizes[1] / 2;
  const int nbuk = (N + NPB - 1) / NPB;
  const int gemmBlocks  = (N + 63) / 64;
  const int buildBlocks = (E + EPB - 1) / EPB;

  char* p = (char*)d_ws;
  unsigned short* wt = (unsigned short*)p; p += (size_t)F_IN * F_OUT * sizeof(unsigned short);
  unsigned short* hb = (unsigned short*)p; p += (size_t)N * F_OUT * sizeof(unsigned short);
  float* a_src = (float*)p;  p += (size_t)N * sizeof(float);
  float* a_dst = (float*)p;  p += (size_t)N * sizeof(float);
  int*   bcnt  = (int*)p;    p += (size_t)nbuk * CNT_STRIDE * sizeof(int);
  p = (char*)(((uintptr_t)p + 63) & ~(uintptr_t)63);
  unsigned* csrw = (unsigned*)p; p += (size_t)nbuk * BCAP * sizeof(unsigned);

  int zero_n = nbuk * CNT_STRIDE;
  int setup_n = (F_IN * F_OUT > zero_n) ? F_IN * F_OUT : zero_n;
  setup_kernel<<<(setup_n + 255) / 256, 256, 0, stream>>>(W, wt, bcnt, nbuk);
  gemm_build_kernel<<<buildBlocks + gemmBlocks, 256, 0, stream>>>(
      x, wt, att_s, att_d, hb, a_src, a_dst, N, ei, bcnt, csrw, E, nbuk, buildBlocks);
  aggregate_kernel<<<nbuk, 256, 0, stream>>>(hb, csrw, a_src, a_dst, bcnt, bias, out, N);
}

// Round 13
// 148.257 us; speedup vs baseline: 1.1022x; 1.0420x over previous
//
#include <hip/hip_runtime.h>
#include <cstdint>
#include <cstddef>

#define F_IN 256
#define F_OUT 128
#define NEG_SLOPE 0.2f
#define NPB 64          // nodes per bucket (dloc packs into 6 bits)
#define MAXBUK 1024     // supports N <= 65536
#define BCAP 2048       // slots per bucket region (mean 1024, 32-sigma safe)
#define EPB 4096        // edges per build block (256 thr x 16) -> 978 total blocks, co-resident
#define WT_STRIDE 72    // 64 + 8 pad (bf16 elems)

typedef short short8 __attribute__((ext_vector_type(8)));
typedef float f32x4 __attribute__((ext_vector_type(4)));

__device__ __forceinline__ unsigned short f2bf_rne(float f) {
  unsigned u = __float_as_uint(f);
  u += 0x7FFFu + ((u >> 16) & 1u);   // round-to-nearest-even
  return (unsigned short)(u >> 16);
}

__device__ __forceinline__ float bf_lo(unsigned u) { return __uint_as_float(u << 16); }
__device__ __forceinline__ float bf_hi(unsigned u) { return __uint_as_float(u & 0xFFFF0000u); }

// ---------------- setup: cast+transpose W -> Wt[n][k] bf16, bucketcnt=0 ----------------
__global__ __launch_bounds__(256) void setup_kernel(const float* __restrict__ W,
                                                    unsigned short* __restrict__ Wt,
                                                    int* __restrict__ bucketcnt, int nbuk) {
  int idx = blockIdx.x * 256 + threadIdx.x;
  if (idx < F_IN * F_OUT) {
    int n = idx & 127, k = idx >> 7;
    Wt[(size_t)n * F_IN + k] = f2bf_rne(W[(size_t)k * F_OUT + n]);
  }
  if (idx < nbuk) bucketcnt[idx] = 0;
}

// ---------------- fused GEMM + edge-bucket build (R6-proven structure) ----------------
// blocks [0, buildBlocks)           : edge multisplit -> packed bucket regions
// blocks [buildBlocks, +gemmBlocks) : h = x @ W (bf16 MFMA) + fused attention logits
// 978 total blocks, 4 blocks/CU resident => full overlap of build under gemm.
__global__ __launch_bounds__(256, 4) void gemm_build_kernel(
    const float* __restrict__ x, const unsigned short* __restrict__ Wt,
    const float* __restrict__ att_src, const float* __restrict__ att_dst,
    unsigned short* __restrict__ hb, float* __restrict__ a_src, float* __restrict__ a_dst,
    int N, const int* __restrict__ ei, int* __restrict__ bucketcnt,
    unsigned* __restrict__ csrw, int E, int nbuk, int buildBlocks) {
  __shared__ __attribute__((aligned(16))) char lds_raw[128 * WT_STRIDE * 2];  // 18432 B
  const int tid = threadIdx.x;

  if ((int)blockIdx.x < buildBlocks) {
    // ---------------- build branch ----------------
    int* lhist = (int*)lds_raw;               // MAXBUK ints
    int* gbase = (int*)(lds_raw + 4096);      // MAXBUK ints
    const int e0 = blockIdx.x * EPB;
    for (int i = tid; i < nbuk; i += 256) lhist[i] = 0;
    __syncthreads();
    int lr[16], lb[16];
    unsigned lw[16];
#pragma unroll
    for (int i = 0; i < 16; ++i) {
      int e = e0 + i * 256 + tid;
      lb[i] = -1;
      if (e < E) {
        int s = ei[e], d = ei[E + e];
        lb[i] = d >> 6;
        lw[i] = ((unsigned)(d & 63) << 26) | (unsigned)s;
        lr[i] = atomicAdd(&lhist[lb[i]], 1);   // LDS atomic: local rank
      }
    }
    __syncthreads();
    for (int i = tid; i < nbuk; i += 256) {
      int c = lhist[i];
      if (c > 0) gbase[i] = atomicAdd(&bucketcnt[i], c);  // one global atomic per bucket
    }
    __syncthreads();
#pragma unroll
    for (int i = 0; i < 16; ++i) {
      if (lb[i] >= 0) {
        int off = gbase[lb[i]] + lr[i];
        if (off < BCAP) csrw[(size_t)lb[i] * BCAP + off] = lw[i];
      }
    }
    return;
  }

  // ---------------- gemm branch ----------------
  unsigned short* wt_l = (unsigned short*)lds_raw;   // 128 * WT_STRIDE bf16
  const int bid  = blockIdx.x - buildBlocks;
  const int lane = tid & 63;
  const int wv   = tid >> 6;
  const int q    = lane >> 4;
  const int l16  = lane & 15;
  const int m0   = bid * 64;
  const int m    = m0 + wv * 16 + l16;
  const int mc   = (m < N) ? m : (N - 1);

  f32x4 acc[8];
#pragma unroll
  for (int i = 0; i < 8; ++i) acc[i] = (f32x4)(0.f);

  const int srow  = tid >> 1;
  const int shalf = tid & 1;

#pragma unroll 1
  for (int t = 0; t < 4; ++t) {
    {
      const unsigned short* g = Wt + (size_t)srow * F_IN + t * 64 + shalf * 32;
      unsigned short* l = wt_l + srow * WT_STRIDE + shalf * 32;
#pragma unroll
      for (int j = 0; j < 4; ++j)
        *(uint4*)(l + j * 8) = *(const uint4*)(g + j * 8);
    }
    __syncthreads();

#pragma unroll
    for (int s = 0; s < 2; ++s) {
      const int kg = t * 64 + s * 32 + q * 8;
      f32x4 a0 = *(const f32x4*)(x + (size_t)mc * F_IN + kg);
      f32x4 a1 = *(const f32x4*)(x + (size_t)mc * F_IN + kg + 4);
      short8 av;
      av[0] = (short)f2bf_rne(a0[0]); av[1] = (short)f2bf_rne(a0[1]);
      av[2] = (short)f2bf_rne(a0[2]); av[3] = (short)f2bf_rne(a0[3]);
      av[4] = (short)f2bf_rne(a1[0]); av[5] = (short)f2bf_rne(a1[1]);
      av[6] = (short)f2bf_rne(a1[2]); av[7] = (short)f2bf_rne(a1[3]);
#pragma unroll
      for (int nt = 0; nt < 8; ++nt) {
        short8 bv = *(const short8*)(wt_l + (nt * 16 + l16) * WT_STRIDE + s * 32 + q * 8);
        acc[nt] = __builtin_amdgcn_mfma_f32_16x16x32_bf16(av, bv, acc[nt], 0, 0, 0);
      }
    }
    __syncthreads();
  }

  float as_c[8], ad_c[8];
#pragma unroll
  for (int nt = 0; nt < 8; ++nt) {
    as_c[nt] = att_src[nt * 16 + l16];
    ad_c[nt] = att_dst[nt * 16 + l16];
  }
  float ps[4] = {0.f, 0.f, 0.f, 0.f}, pd[4] = {0.f, 0.f, 0.f, 0.f};
#pragma unroll
  for (int nt = 0; nt < 8; ++nt)
#pragma unroll
    for (int r = 0; r < 4; ++r) {
      ps[r] += acc[nt][r] * as_c[nt];
      pd[r] += acc[nt][r] * ad_c[nt];
    }
#pragma unroll
  for (int r = 0; r < 4; ++r) {
    int gm = m0 + wv * 16 + q * 4 + r;
    if (gm < N) {
#pragma unroll
      for (int nt = 0; nt < 8; ++nt)
        hb[(size_t)gm * F_OUT + nt * 16 + l16] = f2bf_rne(acc[nt][r]);
    }
  }
#pragma unroll
  for (int r = 0; r < 4; ++r) {
#pragma unroll
    for (int off = 1; off <= 8; off <<= 1) {
      ps[r] += __shfl_xor(ps[r], off, 64);
      pd[r] += __shfl_xor(pd[r], off, 64);
    }
  }
  if (l16 == 0) {
#pragma unroll
    for (int r = 0; r < 4; ++r) {
      int gm = m0 + wv * 16 + q * 4 + r;
      if (gm < N) { a_src[gm] = ps[r]; a_dst[gm] = pd[r]; }
    }
  }
}

// ---------------- aggregate: in-LDS counting sort + register gather (R6-proven) ----------------
// One block per 64-node bucket. Prologue: counting sort into node-sorted LDS list.
// Main loop: 16 lanes/node, 8-slot chunks, shfl broadcast, uint4 row gathers.
// p=exp(leaky(e)) without max shift (|e|<~12; alpha identical after normalization).
__global__ __launch_bounds__(256) void aggregate_kernel(const unsigned short* __restrict__ hb,
                                                        const unsigned* __restrict__ csrw,
                                                        const float* __restrict__ a_src,
                                                        const float* __restrict__ a_dst,
                                                        const int* __restrict__ bucketcnt,
                                                        const float* __restrict__ bias,
                                                        float* __restrict__ out, int N) {
  __shared__ unsigned sw[BCAP];
  __shared__ unsigned sorted[BCAP + NPB];
  __shared__ int start[NPB + 1];
  __shared__ int fill[NPB];
  __shared__ float adl[NPB];
  const int tid = threadIdx.x;
  const int n0  = blockIdx.x * NPB;
  int cnt = bucketcnt[blockIdx.x];
  cnt = (cnt < BCAP) ? cnt : BCAP;

  if (tid < NPB) {
    int n = n0 + tid;
    start[1 + tid] = (n < N) ? 1 : 0;   // self-loop slot
    fill[tid] = 1;                      // slot 0 reserved for self loop
    adl[tid] = (n < N) ? a_dst[n] : 0.f;
  }
  __syncthreads();
  for (int j = tid; j < cnt; j += 256) {
    unsigned w = csrw[(size_t)blockIdx.x * BCAP + j];
    sw[j] = w;
    atomicAdd(&start[1 + (int)(w >> 26)], 1);
  }
  __syncthreads();
  if (tid < NPB) {                      // wave 0: exclusive scan of 64 counts
    int incl = start[1 + tid];
#pragma unroll
    for (int off = 1; off < NPB; off <<= 1) {
      int t = __shfl_up(incl, off, 64);
      if (tid >= off) incl += t;
    }
    start[1 + tid] = incl;
    if (tid == 0) start[0] = 0;
  }
  __syncthreads();
  if (tid < NPB && n0 + tid < N)
    sorted[start[tid]] = ((unsigned)tid << 26) | (unsigned)(n0 + tid);  // self loop
  for (int j = tid; j < cnt; j += 256) {
    unsigned w = sw[j];
    int loc = (int)(w >> 26);
    sorted[start[loc] + atomicAdd(&fill[loc], 1)] = w;
  }
  __syncthreads();

  const int g   = tid >> 4;   // 16 groups; group handles nodes g, g+16, g+32, g+48
  const int l16 = tid & 15;
  const unsigned short* hrow = hb + l16 * 8;
  const float4 bb0 = *(const float4*)(bias + l16 * 8);
  const float4 bb1 = *(const float4*)(bias + l16 * 8 + 4);
#pragma unroll 1
  for (int r = 0; r < 4; ++r) {
    int loc = g + r * 16;
    int n = n0 + loc;
    if (n >= N) continue;
    int b0 = start[loc], b1 = start[loc + 1];
    f32x4 acc0 = (f32x4)(0.f), acc1 = (f32x4)(0.f);
    float s = 0.f;
    for (int jb = b0; jb < b1; jb += 8) {
      int jj = jb + (l16 & 7);
      float p = 0.f;
      int c = 0;
      if (jj < b1) {
        unsigned w = sorted[jj];
        c = (int)(w & 0x03FFFFFFu);
        float e = a_src[c] + adl[loc];
        e = (e > 0.f) ? e : NEG_SLOPE * e;
        p = __expf(e);
      }
      s += (l16 < 8) ? p : 0.f;
#pragma unroll
      for (int k = 0; k < 8; ++k) {
        float pk = __shfl(p, k, 8);
        int   ck = __shfl(c, k, 8);
        const uint4 hv = *(const uint4*)(hrow + (size_t)ck * F_OUT);
        acc0[0] += pk * bf_lo(hv.x); acc0[1] += pk * bf_hi(hv.x);
        acc0[2] += pk * bf_lo(hv.y); acc0[3] += pk * bf_hi(hv.y);
        acc1[0] += pk * bf_lo(hv.z); acc1[1] += pk * bf_hi(hv.z);
        acc1[2] += pk * bf_lo(hv.w); acc1[3] += pk * bf_hi(hv.w);
      }
    }
#pragma unroll
    for (int off = 1; off < 16; off <<= 1) s += __shfl_xor(s, off, 16);

    float sc = 1.f / (s + 1e-16f);
    float4 o0, o1;
    o0.x = acc0[0] * sc + bb0.x;
    o0.y = acc0[1] * sc + bb0.y;
    o0.z = acc0[2] * sc + bb0.z;
    o0.w = acc0[3] * sc + bb0.w;
    o1.x = acc1[0] * sc + bb1.x;
    o1.y = acc1[1] * sc + bb1.y;
    o1.z = acc1[2] * sc + bb1.z;
    o1.w = acc1[3] * sc + bb1.w;
    *(float4*)&out[(size_t)n * F_OUT + l16 * 8]     = o0;
    *(float4*)&out[(size_t)n * F_OUT + l16 * 8 + 4] = o1;
  }
}

// ---------------- launch ----------------
extern "C" void kernel_launch(void* const* d_in, const int* in_sizes, int n_in,
                              void* d_out, int out_size, void* d_ws, size_t ws_size,
                              hipStream_t stream) {
  const float* x     = (const float*)d_in[0];
  const int*   ei    = (const int*)d_in[1];
  const float* W     = (const float*)d_in[2];
  const float* att_s = (const float*)d_in[3];
  const float* att_d = (const float*)d_in[4];
  const float* bias  = (const float*)d_in[5];
  float* out = (float*)d_out;

  const int N = in_sizes[0] / F_IN;
  const int E = in_sizes[1] / 2;
  const int nbuk = (N + NPB - 1) / NPB;
  const int gemmBlocks  = (N + 63) / 64;
  const int buildBlocks = (E + EPB - 1) / EPB;

  char* p = (char*)d_ws;
  unsigned short* wt = (unsigned short*)p; p += (size_t)F_IN * F_OUT * sizeof(unsigned short);
  unsigned short* hb = (unsigned short*)p; p += (size_t)N * F_OUT * sizeof(unsigned short);
  float* a_src = (float*)p;  p += (size_t)N * sizeof(float);
  float* a_dst = (float*)p;  p += (size_t)N * sizeof(float);
  int*   bcnt  = (int*)p;    p += (size_t)nbuk * sizeof(int);
  p = (char*)(((uintptr_t)p + 15) & ~(uintptr_t)15);
  unsigned* csrw = (unsigned*)p; p += (size_t)nbuk * BCAP * sizeof(unsigned);

  int setup_n = (F_IN * F_OUT > nbuk) ? F_IN * F_OUT : nbuk;
  setup_kernel<<<(setup_n + 255) / 256, 256, 0, stream>>>(W, wt, bcnt, nbuk);
  gemm_build_kernel<<<buildBlocks + gemmBlocks, 256, 0, stream>>>(
      x, wt, att_s, att_d, hb, a_src, a_dst, N, ei, bcnt, csrw, E, nbuk, buildBlocks);
  aggregate_kernel<<<nbuk, 256, 0, stream>>>(hb, csrw, a_src, a_dst, bcnt, bias, out, N);
}